// Round 1
// baseline (1160.214 us; speedup 1.0000x reference)
//
#include <hip/hip_runtime.h>
#include <hip/hip_bf16.h>

// Problem constants (Attention_13116830122301):
// x: (4,192,256,256) f32; qkv_w: (576,192); dw_w: (576,1,3,3); proj_w: (192,192);
// temperature: (4,1,1); num_heads=4. Output: (4,192,256,256) f32.
constexpr int BB = 4;
constexpr int C = 192;
constexpr int NH = 4;
constexpr int CPH = 48;       // C / num_heads
constexpr int HH = 256;
constexpr int WI = 256;
constexpr int HW = HH * WI;   // 65536
constexpr int OC3 = 3 * C;    // 576

// Workspace layout (float offsets for the small fp32 region)
constexpr size_t WS_G   = 0;                                  // [B][NH][48][48]
constexpr size_t WS_NQ  = WS_G + (size_t)BB * NH * CPH * CPH; // [B][C]
constexpr size_t WS_NK  = WS_NQ + (size_t)BB * C;             // [B][C]
constexpr size_t WS_M   = WS_NK + (size_t)BB * C;             // [B][192][192]
constexpr size_t WS_END = WS_M + (size_t)BB * C * C;          // 185856 floats

typedef __attribute__((ext_vector_type(8))) short bf16x8;
typedef __attribute__((ext_vector_type(4))) float f32x4;

union FragU { bf16x8 f; uint4 q; uint w[4]; ushort s[8]; };

__device__ inline float b2f(ushort u) {
  union { uint i; float f; } v; v.i = (uint)u << 16; return v.f;
}
__device__ inline ushort f2b(float f) {
  __hip_bfloat16 b = __float2bfloat16(f);
  ushort r; __builtin_memcpy(&r, &b, 2); return r;
}
__device__ inline uint f2b2(float lo, float hi) {
  __hip_bfloat162 h = __float22bfloat162_rn(make_float2(lo, hi));
  uint r; __builtin_memcpy(&r, &h, 4); return r;
}
__device__ inline bf16x8 ld_frag(const ushort* p) {  // 8 bf16, 16-B aligned
  FragU u; u.q = *(const uint4*)p; return u.f;
}
__device__ inline bf16x8 pack8(const float* v) {     // 8 fp32 -> 8 bf16
  FragU u;
#pragma unroll
  for (int i = 0; i < 4; ++i) u.w[i] = f2b2(v[2 * i], v[2 * i + 1]);
  return u.f;
}

// ---------------------------------------------------------------------------
// K1: qkv 1x1 conv, bf16 MFMA. p-tile-STATIONARY: each block owns a 128-px
// strip, stages x[192][128] once into LDS (bf16, XOR-swizzled [p][k] layout,
// 48 KB -> 3 blocks/CU), then loops all 9 o-chunks of 64 against it.
// x is fetched from HBM exactly once (was 9 logical passes / 4.2x measured
// over-fetch in the o-tiled version). B-frag = one swizzled ds_read_b128.
// A-frags from f32 w (L2-resident) + cvt. Wave tile: 64o x 32p, 4 waves in p.
// Swizzle: byte = p*384 + ((k*2) ^ ((p&7)<<4)); bijective per row since
// 384 = 24*16 and (m ^ s) stays in [0,24); spreads the 384-B row stride
// (bank 0 for all lanes otherwise) across all 32 banks.
// ---------------------------------------------------------------------------
constexpr int QPT = 128;  // pixels per block tile

__global__ __launch_bounds__(256) void qkv_mfma_k(const float* __restrict__ x,
                                                  const float* __restrict__ w,
                                                  ushort* __restrict__ y, int b0) {
  alignas(16) __shared__ ushort xs[QPT * C];  // swizzled [p][k] bf16, 48 KB
  const int t = threadIdx.x;
  const int wv = t >> 6, l = t & 63;
  const int lr = l & 15, lg = l >> 4;
  const int p0 = blockIdx.x * QPT;
  const int bl = blockIdx.y;
  const float* xb = x + (size_t)(b0 + bl) * C * HW;

  // ---- stage x tile: 256 threads, 2 k-chunks (of 8) per iteration ----
  {
    const int pl = t & (QPT - 1);
    const int kh = t >> 7;  // 0 or 1
    const float* gp = xb + p0 + pl;
    char* row = (char*)(xs + pl * C);
    const int psw = (pl & 7) << 4;
    for (int it = 0; it < 12; ++it) {
      const int kc = it * 2 + kh;  // 8-k chunk index, 0..23
      const float* g = gp + (size_t)(kc * 8) * HW;
      FragU u;
#pragma unroll
      for (int jp = 0; jp < 4; ++jp) {
        const float lo = g[(size_t)(2 * jp) * HW];
        const float hi = g[(size_t)(2 * jp + 1) * HW];
        u.w[jp] = f2b2(lo, hi);
      }
      *(uint4*)(row + ((kc * 16) ^ psw)) = u.q;
    }
  }
  __syncthreads();

  // ---- sweep all 9 o-chunks against the resident tile ----
  ushort* yb = y + (size_t)bl * OC3 * HW;
  const int pw = wv * 32;  // wave's 32-px sub-strip
  for (int oc = 0; oc < 9; ++oc) {
    const int o0 = oc * 64;
    f32x4 acc[4][2] = {};
    for (int ks = 0; ks < C; ks += 32) {
      bf16x8 afr[4], bfr[2];
#pragma unroll
      for (int mi = 0; mi < 4; ++mi) {
        const float* ap = w + (size_t)(o0 + mi * 16 + lr) * C + ks + lg * 8;
        float av[8];
        *(float4*)(av) = *(const float4*)ap;
        *(float4*)(av + 4) = *(const float4*)(ap + 4);
        afr[mi] = pack8(av);
      }
#pragma unroll
      for (int ni = 0; ni < 2; ++ni) {
        const int p = pw + ni * 16 + lr;
        const int boff = ((ks + lg * 8) * 2) ^ ((p & 7) << 4);
        bfr[ni] = *(const bf16x8*)((const char*)(xs + p * C) + boff);
      }
#pragma unroll
      for (int mi = 0; mi < 4; ++mi)
#pragma unroll
        for (int ni = 0; ni < 2; ++ni)
          acc[mi][ni] = __builtin_amdgcn_mfma_f32_16x16x32_bf16(afr[mi], bfr[ni], acc[mi][ni], 0, 0, 0);
    }
#pragma unroll
    for (int mi = 0; mi < 4; ++mi)
#pragma unroll
      for (int r = 0; r < 4; ++r) {
        const int o = o0 + mi * 16 + lg * 4 + r;
#pragma unroll
        for (int ni = 0; ni < 2; ++ni)
          yb[(size_t)o * HW + (p0 + pw + ni * 16 + lr)] = f2b(acc[mi][ni][r]);
      }
  }
}

// ---------------------------------------------------------------------------
// K2: 3x3 depthwise conv, bf16 in -> bf16 out, 4 px/thread, sliding 3-row
// register window (30 vector loads per 8 output rows). Folds q/k L2 norms.
// Block: (32-row group, channel, batch); thread = (strip s = t&63, rq = t>>6).
// ---------------------------------------------------------------------------
constexpr int DW_RPB = 32;
__global__ __launch_bounds__(256) void dwconv_k(const ushort* __restrict__ raw,
                                                const float* __restrict__ dww,
                                                ushort* __restrict__ dst,
                                                float* __restrict__ Nq,
                                                float* __restrict__ Nk, int b0) {
  const int t = threadIdx.x;
  const int s = t & 63;
  const int rq = t >> 6;
  const int ch = blockIdx.y;
  const int bl = blockIdx.z;
  const int bg = b0 + bl;
  const int y0 = blockIdx.x * DW_RPB + rq * 8;
  const int x4 = s * 4;
  const ushort* cb = raw + ((size_t)bl * OC3 + ch) * HW;
  ushort* ob = dst + ((size_t)bl * OC3 + ch) * HW;
  float wg[9];
#pragma unroll
  for (int i = 0; i < 9; ++i) wg[i] = dww[ch * 9 + i];

  auto load_row = [&](int y, float* r) {
    if ((unsigned)y >= (unsigned)HH) {
#pragma unroll
      for (int i = 0; i < 6; ++i) r[i] = 0.f;
      return;
    }
    const ushort* rp = cb + (size_t)y * WI;
    const ushort4 m = *(const ushort4*)(rp + x4);
    r[1] = b2f(m.x); r[2] = b2f(m.y); r[3] = b2f(m.z); r[4] = b2f(m.w);
    r[0] = (s > 0) ? b2f(rp[x4 - 1]) : 0.f;
    r[5] = (s < 63) ? b2f(rp[x4 + 4]) : 0.f;
  };

  float r0[6], r1[6], r2[6];
  load_row(y0 - 1, r0);
  load_row(y0, r1);
  float nacc = 0.f;
#pragma unroll
  for (int i = 0; i < 8; ++i) {
    const int y = y0 + i;
    load_row(y + 1, r2);
    float o[4];
#pragma unroll
    for (int px = 0; px < 4; ++px) {
      float v = wg[0] * r0[px] + wg[1] * r0[px + 1] + wg[2] * r0[px + 2]
              + wg[3] * r1[px] + wg[4] * r1[px + 1] + wg[5] * r1[px + 2]
              + wg[6] * r2[px] + wg[7] * r2[px + 1] + wg[8] * r2[px + 2];
      o[px] = v;
      nacc += v * v;
    }
    uint2 pk;
    pk.x = f2b2(o[0], o[1]);
    pk.y = f2b2(o[2], o[3]);
    *(uint2*)(ob + (size_t)y * WI + x4) = pk;
#pragma unroll
    for (int k = 0; k < 6; ++k) { r0[k] = r1[k]; r1[k] = r2[k]; }
  }
  if (ch < 2 * C) {  // q or k channel: accumulate L2 norm
#pragma unroll
    for (int off = 32; off > 0; off >>= 1) nacc += __shfl_down(nacc, off);
    __shared__ float red[4];
    if ((t & 63) == 0) red[t >> 6] = nacc;
    __syncthreads();
    if (t == 0) {
      const float tot = red[0] + red[1] + red[2] + red[3];
      if (ch < C) atomicAdd(&Nq[(size_t)bg * C + ch], tot);
      else        atomicAdd(&Nk[(size_t)bg * C + (ch - C)], tot);
    }
  }
}

// ---------------------------------------------------------------------------
// K3: Gram G[i,j] = sum_p qd[i,p] kd[j,p] per (b,head) via MFMA.
// A and B fragments are both contiguous-in-p 16-B loads from [ch][px] bf16 —
// no LDS staging, no transpose. K split over 32 chunks; LDS + global atomics.
// ---------------------------------------------------------------------------
__global__ __launch_bounds__(256) void gram_mfma_k(const ushort* __restrict__ dw,
                                                   float* __restrict__ G, int b0) {
  __shared__ float Gs[CPH][CPH + 1];
  const int t = threadIdx.x;
  const int wv = t >> 6, l = t & 63;
  const int lr = l & 15, lg = l >> 4;
  const int chunk = blockIdx.x;  // 0..31
  const int h = blockIdx.y;
  const int bl = blockIdx.z;
  const int bg = b0 + bl;
  const ushort* qb = dw + ((size_t)bl * OC3 + h * CPH) * HW;
  const ushort* kb = qb + (size_t)C * HW;
  f32x4 acc[3][3] = {};
  for (int it = 0; it < 16; ++it) {
    const int p = chunk * 2048 + it * 128 + wv * 32 + lg * 8;
    bf16x8 afr[3], bfr[3];
#pragma unroll
    for (int mi = 0; mi < 3; ++mi) afr[mi] = ld_frag(qb + (size_t)(mi * 16 + lr) * HW + p);
#pragma unroll
    for (int ni = 0; ni < 3; ++ni) bfr[ni] = ld_frag(kb + (size_t)(ni * 16 + lr) * HW + p);
#pragma unroll
    for (int mi = 0; mi < 3; ++mi)
#pragma unroll
      for (int ni = 0; ni < 3; ++ni)
        acc[mi][ni] = __builtin_amdgcn_mfma_f32_16x16x32_bf16(afr[mi], bfr[ni], acc[mi][ni], 0, 0, 0);
  }
  for (int e = t; e < CPH * (CPH + 1); e += 256) ((float*)Gs)[e] = 0.f;
  __syncthreads();
#pragma unroll
  for (int mi = 0; mi < 3; ++mi)
#pragma unroll
    for (int ni = 0; ni < 3; ++ni)
#pragma unroll
      for (int r = 0; r < 4; ++r)
        atomicAdd(&Gs[mi * 16 + lg * 4 + r][ni * 16 + lr], acc[mi][ni][r]);
  __syncthreads();
  float* Gb = G + ((size_t)bg * NH + h) * CPH * CPH;
  for (int e = t; e < CPH * CPH; e += 256)
    atomicAdd(&Gb[e], Gs[e / CPH][e % CPH]);
}

// ---------------------------------------------------------------------------
// K4: per (b,head): logits = G/(||q_i|| ||k_j||) * temp[h]; softmax rows;
//     M[b][o][h*48+j] = sum_i proj[o][h*48+i] * attn[i][j]   (proj folded in)
// ---------------------------------------------------------------------------
__global__ __launch_bounds__(256) void softmax_M_k(const float* __restrict__ G,
                                                   const float* __restrict__ Nq,
                                                   const float* __restrict__ Nk,
                                                   const float* __restrict__ proj,
                                                   const float* __restrict__ temp,
                                                   float* __restrict__ M, int b0) {
  __shared__ float att[48][49];
  __shared__ float sq[48], sk[48];
  const int t = threadIdx.x;
  const int h = blockIdx.x;
  const int bg = b0 + blockIdx.y;
  const float* Gb = G + ((size_t)bg * NH + h) * CPH * CPH;
  if (t < CPH) sq[t] = 1.f / fmaxf(sqrtf(Nq[(size_t)bg * C + h * CPH + t]), 1e-12f);
  else if (t < 96) sk[t - CPH] = 1.f / fmaxf(sqrtf(Nk[(size_t)bg * C + h * CPH + (t - CPH)]), 1e-12f);
  __syncthreads();
  const float tp = temp[h];
  for (int e = t; e < CPH * CPH; e += 256) {
    const int i = e / CPH, j = e % CPH;
    att[i][j] = Gb[e] * sq[i] * sk[j] * tp;
  }
  __syncthreads();
  if (t < CPH) {
    float m = -1e30f;
    for (int j = 0; j < CPH; ++j) m = fmaxf(m, att[t][j]);
    float sum = 0.f;
    for (int j = 0; j < CPH; ++j) { const float ev = expf(att[t][j] - m); att[t][j] = ev; sum += ev; }
    const float inv = 1.f / sum;
    for (int j = 0; j < CPH; ++j) att[t][j] *= inv;
  }
  __syncthreads();
  float* Mb = M + (size_t)bg * C * C;
  for (int e = t; e < C * CPH; e += 256) {
    const int o = e / CPH, j = e % CPH;
    const float* pr = proj + (size_t)o * C + h * CPH;
    float s = 0.f;
#pragma unroll 8
    for (int i = 0; i < CPH; ++i) s += pr[i] * att[i][j];
    Mb[(size_t)o * C + h * CPH + j] = s;
  }
}

// ---------------------------------------------------------------------------
// K5: out[bg,o,p] = sum_c M_b[o,c] * vd[c,p]; bf16 MFMA, no LDS.
// A = M_b (fp32, L2-resident) direct 16-B loads + cvt; B = vd bf16 strided
// ushort loads (L2-warm). Block tile 64o x 256p.
// ---------------------------------------------------------------------------
__global__ __launch_bounds__(256) void out_mfma_k(const ushort* __restrict__ dw,
                                                  const float* __restrict__ Mg,
                                                  float* __restrict__ out, int b0) {
  const int t = threadIdx.x;
  const int wv = t >> 6, l = t & 63;
  const int lr = l & 15, lg = l >> 4;
  const int p0 = blockIdx.x * 256 + wv * 64;
  const int o0 = blockIdx.y * 64;
  const int bl = blockIdx.z;
  const int bg = b0 + bl;
  const float* Mb = Mg + (size_t)bg * C * C;
  const ushort* vb = dw + ((size_t)bl * OC3 + 2 * C) * HW;
  f32x4 acc[4][4] = {};
  for (int ks = 0; ks < C; ks += 32) {
    bf16x8 afr[4], bfr[4];
#pragma unroll
    for (int mi = 0; mi < 4; ++mi) {
      const float* ap = Mb + (size_t)(o0 + mi * 16 + lr) * C + ks + lg * 8;
      float av[8];
      *(float4*)(av) = *(const float4*)ap;
      *(float4*)(av + 4) = *(const float4*)(ap + 4);
      afr[mi] = pack8(av);
    }
#pragma unroll
    for (int ni = 0; ni < 4; ++ni) {
      const ushort* bp = vb + (size_t)(ks + lg * 8) * HW + (p0 + ni * 16 + lr);
      FragU u;
#pragma unroll
      for (int jp = 0; jp < 4; ++jp) {
        const uint u0 = bp[(size_t)(2 * jp) * HW];
        const uint u1 = bp[(size_t)(2 * jp + 1) * HW];
        u.w[jp] = u0 | (u1 << 16);
      }
      bfr[ni] = u.f;
    }
#pragma unroll
    for (int mi = 0; mi < 4; ++mi)
#pragma unroll
      for (int ni = 0; ni < 4; ++ni)
        acc[mi][ni] = __builtin_amdgcn_mfma_f32_16x16x32_bf16(afr[mi], bfr[ni], acc[mi][ni], 0, 0, 0);
  }
#pragma unroll
  for (int mi = 0; mi < 4; ++mi)
#pragma unroll
    for (int r = 0; r < 4; ++r) {
      const int o = o0 + mi * 16 + lg * 4 + r;
#pragma unroll
      for (int ni = 0; ni < 4; ++ni)
        out[((size_t)bg * C + o) * HW + (p0 + ni * 16 + lr)] = acc[mi][ni][r];
    }
}

// ---------------------------------------------------------------------------
extern "C" void kernel_launch(void* const* d_in, const int* in_sizes, int n_in,
                              void* d_out, int out_size, void* d_ws, size_t ws_size,
                              hipStream_t stream) {
  const float* x      = (const float*)d_in[0];
  const float* qkv_w  = (const float*)d_in[1];
  const float* dw_w   = (const float*)d_in[2];
  const float* proj_w = (const float*)d_in[3];
  const float* temp   = (const float*)d_in[4];
  float* out = (float*)d_out;
  float* ws = (float*)d_ws;
  float* G  = ws + WS_G;
  float* Nq = ws + WS_NQ;
  float* Nk = ws + WS_NK;
  float* M  = ws + WS_M;

  const size_t small = WS_END * sizeof(float);              // 743424 B
  const size_t unit = (size_t)OC3 * HW * 2 * sizeof(ushort); // raw+dw bf16 per batch = 150,994,944 B
  int nb = 1;
  if (ws_size >= small + 4 * unit) nb = 4;       // 604.7 MB — proven to fit (round 1 ran this tier)
  else if (ws_size >= small + 2 * unit) nb = 2;
  ushort* raw = (ushort*)((char*)d_ws + small);
  ushort* dwb = raw + (size_t)nb * OC3 * HW;

  // zero accumulators (G, Nq, Nk) — ws is poisoned before each call
  hipMemsetAsync(G, 0, (WS_M - WS_G) * sizeof(float), stream);

  for (int b0 = 0; b0 < BB; b0 += nb) {
    qkv_mfma_k<<<dim3(HW / QPT, nb), 256, 0, stream>>>(x, qkv_w, raw, b0);
    dwconv_k<<<dim3(HH / DW_RPB, OC3, nb), 256, 0, stream>>>(raw, dw_w, dwb, Nq, Nk, b0);
    gram_mfma_k<<<dim3(32, NH, nb), 256, 0, stream>>>(dwb, G, b0);
    softmax_M_k<<<dim3(NH, nb), 256, 0, stream>>>(G, Nq, Nk, proj_w, temp, M, b0);
    out_mfma_k<<<dim3(HW / 256, C / 64, nb), 256, 0, stream>>>(dwb, M, out, b0);
  }
}

// Round 2
// 790.806 us; speedup vs baseline: 1.4671x; 1.4671x over previous
//
#include <hip/hip_runtime.h>
#include <hip/hip_bf16.h>

// Problem constants (Attention_13116830122301):
// x: (4,192,256,256) f32; qkv_w: (576,192); dw_w: (576,1,3,3); proj_w: (192,192);
// temperature: (4,1,1); num_heads=4. Output: (4,192,256,256) f32.
constexpr int BB = 4;
constexpr int C = 192;
constexpr int NH = 4;
constexpr int CPH = 48;       // C / num_heads
constexpr int HH = 256;
constexpr int WI = 256;
constexpr int HW = HH * WI;   // 65536
constexpr int OC3 = 3 * C;    // 576

// ---- workspace layout ----
// fp32 region (float offsets):
constexpr size_t WS_G    = 0;                                   // [B][NH][48][48]
constexpr size_t WS_NQ   = WS_G + (size_t)BB * NH * CPH * CPH;  // [B][C]
constexpr size_t WS_NK   = WS_NQ + (size_t)BB * C;              // [B][C]
constexpr size_t WS_FEND = WS_NK + (size_t)BB * C;              // 38400 floats
// bf16 (ushort) regions, byte offsets:
constexpr size_t WP_OFF  = WS_FEND * 4;                         // wpA: qkv_w packed, 221184 B
constexpr size_t WP_SZ   = (size_t)OC3 * C * 2;
constexpr size_t MP_OFF  = WP_OFF + WP_SZ;                      // Mpack: [B] packed M, 294912 B
constexpr size_t MP_SZ   = (size_t)BB * C * C * 2;
constexpr size_t SMALL   = MP_OFF + MP_SZ;                      // 669696 B

constexpr int MP_BSTRIDE = C * C;  // ushorts per batch in Mpack (36864)

typedef __attribute__((ext_vector_type(8))) short bf16x8;
typedef __attribute__((ext_vector_type(4))) float f32x4;

union FragU { bf16x8 f; uint4 q; uint w[4]; ushort s[8]; };

__device__ inline float b2f(ushort u) {
  union { uint i; float f; } v; v.i = (uint)u << 16; return v.f;
}
__device__ inline ushort f2b(float f) {
  __hip_bfloat16 b = __float2bfloat16(f);
  ushort r; __builtin_memcpy(&r, &b, 2); return r;
}
__device__ inline uint f2b2(float lo, float hi) {
  __hip_bfloat162 h = __float22bfloat162_rn(make_float2(lo, hi));
  uint r; __builtin_memcpy(&r, &h, 4); return r;
}
__device__ inline bf16x8 ld_frag(const ushort* p) {  // 8 bf16, 16-B aligned
  FragU u; u.q = *(const uint4*)p; return u.f;
}
__device__ inline bf16x8 pack8(const float* v) {     // 8 fp32 -> 8 bf16
  FragU u;
#pragma unroll
  for (int i = 0; i < 4; ++i) u.w[i] = f2b2(v[2 * i], v[2 * i + 1]);
  return u.f;
}

// ---------------------------------------------------------------------------
// K0: pack qkv_w (576x192 f32) -> bf16 in MFMA A-fragment layout:
//   wpA[((ot*24 + kc)*16 + lr)*8 + l8] = bf16(w[ot*16+lr][kc*8+l8])
// so a wave's A-frag load (lanes: lr=o%16, lg->kc) is ONE contiguous 1 KB
// block per instruction (was a 64-cache-line gather — the round-1 serializer).
// ---------------------------------------------------------------------------
__global__ __launch_bounds__(256) void pack_w_k(const float* __restrict__ w,
                                                ushort* __restrict__ wpA) {
  const int idx = blockIdx.x * 256 + threadIdx.x;  // 0..110591, output-linear
  if (idx >= OC3 * C) return;
  const int l8 = idx & 7;
  const int lr = (idx >> 3) & 15;
  const int kc = (idx >> 7) % 24;
  const int ot = (idx >> 7) / 24;
  const int o = ot * 16 + lr, k = kc * 8 + l8;
  wpA[idx] = f2b(w[(size_t)o * C + k]);
}

// ---------------------------------------------------------------------------
// K1: qkv 1x1 conv, bf16 MFMA. p-tile-STATIONARY: each block owns a 128-px
// strip, stages x[192][128] once into LDS (bf16, XOR-swizzled [p][k] layout,
// 48 KB -> 3 blocks/CU), then loops all 9 o-chunks of 64 against it.
// A-frags now come from the pre-packed wpA (one contiguous 16-B load/lane,
// L1-resident 24.5 KB slice, zero cvt); B-frags are swizzled ds_read_b128.
// Only one __syncthreads in the whole kernel.
// ---------------------------------------------------------------------------
constexpr int QPT = 128;  // pixels per block tile

__global__ __launch_bounds__(256) void qkv_mfma_k(const float* __restrict__ x,
                                                  const ushort* __restrict__ wpA,
                                                  ushort* __restrict__ y, int b0) {
  alignas(16) __shared__ ushort xs[QPT * C];  // swizzled [p][k] bf16, 48 KB
  const int t = threadIdx.x;
  const int wv = t >> 6, l = t & 63;
  const int lr = l & 15, lg = l >> 4;
  const int p0 = blockIdx.x * QPT;
  const int bl = blockIdx.y;
  const float* xb = x + (size_t)(b0 + bl) * C * HW;

  // ---- stage x tile: 256 threads, 2 k-chunks (of 8) per iteration ----
  {
    const int pl = t & (QPT - 1);
    const int kh = t >> 7;  // 0 or 1
    const float* gp = xb + p0 + pl;
    char* row = (char*)(xs + pl * C);
    const int psw = (pl & 7) << 4;
    for (int it = 0; it < 12; ++it) {
      const int kc = it * 2 + kh;  // 8-k chunk index, 0..23
      const float* g = gp + (size_t)(kc * 8) * HW;
      FragU u;
#pragma unroll
      for (int jp = 0; jp < 4; ++jp) {
        const float lo = g[(size_t)(2 * jp) * HW];
        const float hi = g[(size_t)(2 * jp + 1) * HW];
        u.w[jp] = f2b2(lo, hi);
      }
      *(uint4*)(row + ((kc * 16) ^ psw)) = u.q;
    }
  }
  __syncthreads();

  // ---- sweep all 9 o-chunks against the resident tile ----
  ushort* yb = y + (size_t)bl * OC3 * HW;
  const int pw = wv * 32;  // wave's 32-px sub-strip
  for (int oc = 0; oc < 9; ++oc) {
    const int o0 = oc * 64;
    f32x4 acc[4][2] = {};
    for (int ks = 0; ks < C; ks += 32) {
      bf16x8 afr[4], bfr[2];
#pragma unroll
      for (int mi = 0; mi < 4; ++mi) {
        const int ot = oc * 4 + mi;
        const int kc = (ks >> 3) + lg;
        afr[mi] = ld_frag(wpA + (size_t)((ot * 24 + kc) * 16 + lr) * 8);
      }
#pragma unroll
      for (int ni = 0; ni < 2; ++ni) {
        const int p = pw + ni * 16 + lr;
        const int boff = ((ks + lg * 8) * 2) ^ ((p & 7) << 4);
        bfr[ni] = *(const bf16x8*)((const char*)(xs + p * C) + boff);
      }
#pragma unroll
      for (int mi = 0; mi < 4; ++mi)
#pragma unroll
        for (int ni = 0; ni < 2; ++ni)
          acc[mi][ni] = __builtin_amdgcn_mfma_f32_16x16x32_bf16(afr[mi], bfr[ni], acc[mi][ni], 0, 0, 0);
    }
#pragma unroll
    for (int mi = 0; mi < 4; ++mi)
#pragma unroll
      for (int r = 0; r < 4; ++r) {
        const int o = o0 + mi * 16 + lg * 4 + r;
#pragma unroll
        for (int ni = 0; ni < 2; ++ni)
          yb[(size_t)o * HW + (p0 + pw + ni * 16 + lr)] = f2b(acc[mi][ni][r]);
      }
  }
}

// ---------------------------------------------------------------------------
// K2: 3x3 depthwise conv, bf16 in -> bf16 out, 4 px/thread, sliding 3-row
// register window (30 vector loads per 8 output rows). Folds q/k L2 norms.
// Block: (32-row group, channel, batch); thread = (strip s = t&63, rq = t>>6).
// ---------------------------------------------------------------------------
constexpr int DW_RPB = 32;
__global__ __launch_bounds__(256) void dwconv_k(const ushort* __restrict__ raw,
                                                const float* __restrict__ dww,
                                                ushort* __restrict__ dst,
                                                float* __restrict__ Nq,
                                                float* __restrict__ Nk, int b0) {
  const int t = threadIdx.x;
  const int s = t & 63;
  const int rq = t >> 6;
  const int ch = blockIdx.y;
  const int bl = blockIdx.z;
  const int bg = b0 + bl;
  const int y0 = blockIdx.x * DW_RPB + rq * 8;
  const int x4 = s * 4;
  const ushort* cb = raw + ((size_t)bl * OC3 + ch) * HW;
  ushort* ob = dst + ((size_t)bl * OC3 + ch) * HW;
  float wg[9];
#pragma unroll
  for (int i = 0; i < 9; ++i) wg[i] = dww[ch * 9 + i];

  auto load_row = [&](int y, float* r) {
    if ((unsigned)y >= (unsigned)HH) {
#pragma unroll
      for (int i = 0; i < 6; ++i) r[i] = 0.f;
      return;
    }
    const ushort* rp = cb + (size_t)y * WI;
    const ushort4 m = *(const ushort4*)(rp + x4);
    r[1] = b2f(m.x); r[2] = b2f(m.y); r[3] = b2f(m.z); r[4] = b2f(m.w);
    r[0] = (s > 0) ? b2f(rp[x4 - 1]) : 0.f;
    r[5] = (s < 63) ? b2f(rp[x4 + 4]) : 0.f;
  };

  float r0[6], r1[6], r2[6];
  load_row(y0 - 1, r0);
  load_row(y0, r1);
  float nacc = 0.f;
#pragma unroll
  for (int i = 0; i < 8; ++i) {
    const int y = y0 + i;
    load_row(y + 1, r2);
    float o[4];
#pragma unroll
    for (int px = 0; px < 4; ++px) {
      float v = wg[0] * r0[px] + wg[1] * r0[px + 1] + wg[2] * r0[px + 2]
              + wg[3] * r1[px] + wg[4] * r1[px + 1] + wg[5] * r1[px + 2]
              + wg[6] * r2[px] + wg[7] * r2[px + 1] + wg[8] * r2[px + 2];
      o[px] = v;
      nacc += v * v;
    }
    uint2 pk;
    pk.x = f2b2(o[0], o[1]);
    pk.y = f2b2(o[2], o[3]);
    *(uint2*)(ob + (size_t)y * WI + x4) = pk;
#pragma unroll
    for (int k = 0; k < 6; ++k) { r0[k] = r1[k]; r1[k] = r2[k]; }
  }
  if (ch < 2 * C) {  // q or k channel: accumulate L2 norm
#pragma unroll
    for (int off = 32; off > 0; off >>= 1) nacc += __shfl_down(nacc, off);
    __shared__ float red[4];
    if ((t & 63) == 0) red[t >> 6] = nacc;
    __syncthreads();
    if (t == 0) {
      const float tot = red[0] + red[1] + red[2] + red[3];
      if (ch < C) atomicAdd(&Nq[(size_t)bg * C + ch], tot);
      else        atomicAdd(&Nk[(size_t)bg * C + (ch - C)], tot);
    }
  }
}

// ---------------------------------------------------------------------------
// K3: Gram G[i,j] = sum_p qd[i,p] kd[j,p] per (b,head) via MFMA.
// A and B fragments are both contiguous-in-p 16-B loads from [ch][px] bf16 —
// no LDS staging, no transpose. K split over 32 chunks; LDS + global atomics.
// ---------------------------------------------------------------------------
__global__ __launch_bounds__(256) void gram_mfma_k(const ushort* __restrict__ dw,
                                                   float* __restrict__ G, int b0) {
  __shared__ float Gs[CPH][CPH + 1];
  const int t = threadIdx.x;
  const int wv = t >> 6, l = t & 63;
  const int lr = l & 15, lg = l >> 4;
  const int chunk = blockIdx.x;  // 0..31
  const int h = blockIdx.y;
  const int bl = blockIdx.z;
  const int bg = b0 + bl;
  const ushort* qb = dw + ((size_t)bl * OC3 + h * CPH) * HW;
  const ushort* kb = qb + (size_t)C * HW;
  f32x4 acc[3][3] = {};
  for (int it = 0; it < 16; ++it) {
    const int p = chunk * 2048 + it * 128 + wv * 32 + lg * 8;
    bf16x8 afr[3], bfr[3];
#pragma unroll
    for (int mi = 0; mi < 3; ++mi) afr[mi] = ld_frag(qb + (size_t)(mi * 16 + lr) * HW + p);
#pragma unroll
    for (int ni = 0; ni < 3; ++ni) bfr[ni] = ld_frag(kb + (size_t)(ni * 16 + lr) * HW + p);
#pragma unroll
    for (int mi = 0; mi < 3; ++mi)
#pragma unroll
      for (int ni = 0; ni < 3; ++ni)
        acc[mi][ni] = __builtin_amdgcn_mfma_f32_16x16x32_bf16(afr[mi], bfr[ni], acc[mi][ni], 0, 0, 0);
  }
  for (int e = t; e < CPH * (CPH + 1); e += 256) ((float*)Gs)[e] = 0.f;
  __syncthreads();
#pragma unroll
  for (int mi = 0; mi < 3; ++mi)
#pragma unroll
    for (int ni = 0; ni < 3; ++ni)
#pragma unroll
      for (int r = 0; r < 4; ++r)
        atomicAdd(&Gs[mi * 16 + lg * 4 + r][ni * 16 + lr], acc[mi][ni][r]);
  __syncthreads();
  float* Gb = G + ((size_t)bg * NH + h) * CPH * CPH;
  for (int e = t; e < CPH * CPH; e += 256)
    atomicAdd(&Gb[e], Gs[e / CPH][e % CPH]);
}

// ---------------------------------------------------------------------------
// K4: per (b,head): logits = G/(||q_i|| ||k_j||) * temp[h]; softmax rows;
//     M[o][h*48+j] = sum_i proj[o][h*48+i] * attn[i][j]   (proj folded in).
// Emits M directly as bf16 in MFMA A-fragment layout (Mpack) — K5 reads it
// with one contiguous 16-B load/lane (kills K5's fp32 64-line gather).
// Numerics unchanged: K5 rounded M to bf16 anyway.
// ---------------------------------------------------------------------------
__global__ __launch_bounds__(256) void softmax_M_k(const float* __restrict__ G,
                                                   const float* __restrict__ Nq,
                                                   const float* __restrict__ Nk,
                                                   const float* __restrict__ proj,
                                                   const float* __restrict__ temp,
                                                   ushort* __restrict__ Mpack, int b0) {
  __shared__ float att[48][49];
  __shared__ float sq[48], sk[48];
  const int t = threadIdx.x;
  const int h = blockIdx.x;
  const int bg = b0 + blockIdx.y;
  const float* Gb = G + ((size_t)bg * NH + h) * CPH * CPH;
  if (t < CPH) sq[t] = 1.f / fmaxf(sqrtf(Nq[(size_t)bg * C + h * CPH + t]), 1e-12f);
  else if (t < 96) sk[t - CPH] = 1.f / fmaxf(sqrtf(Nk[(size_t)bg * C + h * CPH + (t - CPH)]), 1e-12f);
  __syncthreads();
  const float tp = temp[h];
  for (int e = t; e < CPH * CPH; e += 256) {
    const int i = e / CPH, j = e % CPH;
    att[i][j] = Gb[e] * sq[i] * sk[j] * tp;
  }
  __syncthreads();
  if (t < CPH) {
    float m = -1e30f;
    for (int j = 0; j < CPH; ++j) m = fmaxf(m, att[t][j]);
    float sum = 0.f;
    for (int j = 0; j < CPH; ++j) { const float ev = expf(att[t][j] - m); att[t][j] = ev; sum += ev; }
    const float inv = 1.f / sum;
    for (int j = 0; j < CPH; ++j) att[t][j] *= inv;
  }
  __syncthreads();
  ushort* Mp = Mpack + (size_t)bg * MP_BSTRIDE;
  for (int e = t; e < C * CPH; e += 256) {
    const int o = e / CPH, j = e % CPH;
    const float* pr = proj + (size_t)o * C + h * CPH;
    float s = 0.f;
#pragma unroll 8
    for (int i = 0; i < CPH; ++i) s += pr[i] * att[i][j];
    const int c = h * CPH + j;  // global k index
    Mp[(size_t)(o >> 4) * 3072 + (c >> 3) * 128 + (o & 15) * 8 + (c & 7)] = f2b(s);
  }
}

// ---------------------------------------------------------------------------
// K5: out[bg,o,p] = sum_c M_b[o,c] * vd[c,p]; bf16 MFMA, no LDS.
// A = Mpack (bf16, A-frag layout, one contiguous load); B = vd bf16 strided
// ushort loads (L2-warm). Block tile 64o x 256p.
// ---------------------------------------------------------------------------
__global__ __launch_bounds__(256) void out_mfma_k(const ushort* __restrict__ dw,
                                                  const ushort* __restrict__ Mpack,
                                                  float* __restrict__ out, int b0) {
  const int t = threadIdx.x;
  const int wv = t >> 6, l = t & 63;
  const int lr = l & 15, lg = l >> 4;
  const int p0 = blockIdx.x * 256 + wv * 64;
  const int o0 = blockIdx.y * 64;
  const int bl = blockIdx.z;
  const int bg = b0 + bl;
  const ushort* Mp = Mpack + (size_t)bg * MP_BSTRIDE;
  const ushort* vb = dw + ((size_t)bl * OC3 + 2 * C) * HW;
  f32x4 acc[4][4] = {};
  for (int ks = 0; ks < C; ks += 32) {
    bf16x8 afr[4], bfr[4];
#pragma unroll
    for (int mi = 0; mi < 4; ++mi) {
      const int ot = (o0 >> 4) + mi;
      const int kc = (ks >> 3) + lg;
      afr[mi] = ld_frag(Mp + (size_t)((ot * 24 + kc) * 16 + lr) * 8);
    }
#pragma unroll
    for (int ni = 0; ni < 4; ++ni) {
      const ushort* bp = vb + (size_t)(ks + lg * 8) * HW + (p0 + ni * 16 + lr);
      FragU u;
#pragma unroll
      for (int jp = 0; jp < 4; ++jp) {
        const uint u0 = bp[(size_t)(2 * jp) * HW];
        const uint u1 = bp[(size_t)(2 * jp + 1) * HW];
        u.w[jp] = u0 | (u1 << 16);
      }
      bfr[ni] = u.f;
    }
#pragma unroll
    for (int mi = 0; mi < 4; ++mi)
#pragma unroll
      for (int ni = 0; ni < 4; ++ni)
        acc[mi][ni] = __builtin_amdgcn_mfma_f32_16x16x32_bf16(afr[mi], bfr[ni], acc[mi][ni], 0, 0, 0);
  }
#pragma unroll
  for (int mi = 0; mi < 4; ++mi)
#pragma unroll
    for (int r = 0; r < 4; ++r) {
      const int o = o0 + mi * 16 + lg * 4 + r;
#pragma unroll
      for (int ni = 0; ni < 4; ++ni)
        out[((size_t)bg * C + o) * HW + (p0 + ni * 16 + lr)] = acc[mi][ni][r];
    }
}

// ---------------------------------------------------------------------------
extern "C" void kernel_launch(void* const* d_in, const int* in_sizes, int n_in,
                              void* d_out, int out_size, void* d_ws, size_t ws_size,
                              hipStream_t stream) {
  const float* x      = (const float*)d_in[0];
  const float* qkv_w  = (const float*)d_in[1];
  const float* dw_w   = (const float*)d_in[2];
  const float* proj_w = (const float*)d_in[3];
  const float* temp   = (const float*)d_in[4];
  float* out = (float*)d_out;
  float* ws = (float*)d_ws;
  float* G  = ws + WS_G;
  float* Nq = ws + WS_NQ;
  float* Nk = ws + WS_NK;
  ushort* wpA   = (ushort*)((char*)d_ws + WP_OFF);
  ushort* Mpack = (ushort*)((char*)d_ws + MP_OFF);

  const size_t unit = (size_t)OC3 * HW * 2 * sizeof(ushort); // raw+dw bf16 per batch = 150,994,944 B
  int nb = 1;
  if (ws_size >= SMALL + 4 * unit) nb = 4;       // ~604.6 MB — this tier ran in rounds 0-1
  else if (ws_size >= SMALL + 2 * unit) nb = 2;
  ushort* raw = (ushort*)((char*)d_ws + SMALL);
  ushort* dwb = raw + (size_t)nb * OC3 * HW;

  // zero accumulators (G, Nq, Nk) — ws is poisoned before each call
  hipMemsetAsync(G, 0, WS_FEND * sizeof(float), stream);
  // pack qkv_w once into A-fragment layout
  pack_w_k<<<dim3((OC3 * C + 255) / 256), 256, 0, stream>>>(qkv_w, wpA);

  for (int b0 = 0; b0 < BB; b0 += nb) {
    qkv_mfma_k<<<dim3(HW / QPT, nb), 256, 0, stream>>>(x, wpA, raw, b0);
    dwconv_k<<<dim3(HH / DW_RPB, OC3, nb), 256, 0, stream>>>(raw, dw_w, dwb, Nq, Nk, b0);
    gram_mfma_k<<<dim3(32, NH, nb), 256, 0, stream>>>(dwb, G, b0);
    softmax_M_k<<<dim3(NH, nb), 256, 0, stream>>>(G, Nq, Nk, proj_w, temp, Mpack, b0);
    out_mfma_k<<<dim3(HW / 256, C / 64, nb), 256, 0, stream>>>(dwb, Mpack, out, b0);
  }
}